// Round 3
// baseline (1125.374 us; speedup 1.0000x reference)
//
#include <hip/hip_runtime.h>

// ---------------------------------------------------------------------------
// H2Q knot kernel: embed -> 8 doubling quaternion expansion steps ->
// 6 quaternion-linear+normalize layers -> vocab head (+ stability loss).
// Strategy: expand Hamilton-product weights into real FP16 matrices, run all
// wide steps as MFMA GEMMs (m97 structure: 128x128 tile, 16x16x32 f16,
// global_load_lds width-16 staging) with fused epilogues.
// R3 change: mfma(Act, W) operand order -> D row=token, col=n. Epilogue
// loads/stores are lane-contiguous along n (32-64B segments vs 8B @ 2KB
// stride before); quaternion normalize crosses 4 adjacent lanes via
// __shfl_xor(1,2). Predicted: WRITE_SIZE 109->68MB/layer, 140->~100us/layer.
// ---------------------------------------------------------------------------

typedef _Float16 f16x8 __attribute__((ext_vector_type(8)));
typedef float    f32x4 __attribute__((ext_vector_type(4)));

#define GL2LDS16(gp, lp) __builtin_amdgcn_global_load_lds(                     \
    (const __attribute__((address_space(1))) void*)(gp),                       \
    (__attribute__((address_space(3))) void*)(lp), 16, 0, 0)

__device__ __forceinline__ unsigned short f2h(float f) {
  union { _Float16 h; unsigned short u; } c;
  c.h = (_Float16)f;                       // RNE
  return c.u;
}
__device__ __forceinline__ float h2f(unsigned short u) {
  union { unsigned short u; _Float16 h; } c;
  c.u = u;
  return (float)c.h;
}

// ---------------------------------------------------------------------------
// Weight expansion: quaternion weights [4][cq][cq] -> real fp16 matrix
// E[n][k], n=4o+a (out), k=4i+b (in), rows >= 4cq zero-padded.
// ---------------------------------------------------------------------------
__global__ __launch_bounds__(256) void expand_ham(
    const float* __restrict__ w, unsigned short* __restrict__ out,
    int cq, int kbits, int total) {
  int id = blockIdx.x * 256 + threadIdx.x;
  if (id >= total) return;
  const int K = 1 << kbits;
  const int n = id >> kbits;
  const int k = id & (K - 1);
  float val = 0.f;
  if (n < 4 * cq) {
    const int o = n >> 2, a = n & 3, i = k >> 2, b = k & 3;
    const int   comp[4][4] = {{0,1,2,3},{1,0,3,2},{2,3,0,1},{3,2,1,0}};
    const float sgn [4][4] = {{1.f,-1.f,-1.f,-1.f},{1.f,1.f,1.f,-1.f},
                              {1.f,-1.f,1.f,1.f},{1.f,1.f,-1.f,1.f}};
    val = sgn[a][b] * w[comp[a][b] * cq * cq + o * cq + i];
  }
  out[id] = f2h(val);
}

__global__ __launch_bounds__(256) void conv_head(
    const float* __restrict__ wh, unsigned short* __restrict__ out) {
  int id = blockIdx.x * 256 + threadIdx.x;   // 384*1024 threads
  int v = id >> 10, k = id & 1023;
  out[id] = f2h(v < 257 ? wh[v * 1024 + k] : 0.f);
}

// ---------------------------------------------------------------------------
// Embed + expansion steps 0..3 (cq=1,2,4,8), one token per thread (weights are
// wave-uniform -> scalar-cached broadcast loads). Output: fp16 [32768][64].
// ---------------------------------------------------------------------------
template <int CQ>
__device__ __forceinline__ void exp_step(float (&q)[16][4],
                                         const float* __restrict__ w) {
  float d[CQ][4];
#pragma unroll
  for (int o = 0; o < CQ; o++) {
    float pr = 0.f, pi = 0.f, pj = 0.f, pk = 0.f;
#pragma unroll
    for (int i = 0; i < CQ; i++) {
      const float wr = w[0 * CQ * CQ + o * CQ + i];
      const float wi = w[1 * CQ * CQ + o * CQ + i];
      const float wj = w[2 * CQ * CQ + o * CQ + i];
      const float wk = w[3 * CQ * CQ + o * CQ + i];
      const float qr = q[i][0], qi = q[i][1], qj = q[i][2], qk = q[i][3];
      pr += wr * qr - wi * qi - wj * qj - wk * qk;
      pi += wi * qr + wr * qi + wk * qj - wj * qk;
      pj += wj * qr - wk * qi + wr * qj + wi * qk;
      pk += wk * qr + wj * qi - wi * qj + wr * qk;
    }
    d[o][0] = tanhf(pr); d[o][1] = tanhf(pi);
    d[o][2] = tanhf(pj); d[o][3] = tanhf(pk);
  }
#pragma unroll
  for (int o = 0; o < CQ; o++)
#pragma unroll
    for (int a = 0; a < 4; a++) {
      const float dd = d[o][a], qq = q[o][a];
      q[o][a]      = qq + dd;
      q[CQ + o][a] = qq - dd;
    }
}

__global__ __launch_bounds__(256) void embed_expand(
    const int* __restrict__ x, const float* __restrict__ emb,
    const float* __restrict__ w0, const float* __restrict__ w1,
    const float* __restrict__ w2, const float* __restrict__ w3,
    unsigned short* __restrict__ out) {
  const int t = blockIdx.x * 256 + threadIdx.x;  // 32768 tokens
  float q[16][4];
  const int v = x[t];
  const float4 e = *(const float4*)(emb + v * 4);
  q[0][0] = e.x; q[0][1] = e.y; q[0][2] = e.z; q[0][3] = e.w;
  exp_step<1>(q, w0);
  exp_step<2>(q, w1);
  exp_step<4>(q, w2);
  exp_step<8>(q, w3);
  ushort4* o4 = (ushort4*)(out + (size_t)t * 64);
#pragma unroll
  for (int c = 0; c < 16; c++) {
    ushort4 u;
    u.x = f2h(q[c][0]); u.y = f2h(q[c][1]);
    u.z = f2h(q[c][2]); u.w = f2h(q[c][3]);
    o4[c] = u;
  }
}

// ---------------------------------------------------------------------------
// Fused GEMM: D[token][n] = sum_k Act[token][k] * W[n][k] (both fp16, k-
// contiguous). 128x128 block tile, 4 waves each 64(token)x64(n), 4x4 of
// 16x16x32 MFMA with operands (Act_frag, W_frag) -> C/D: row=token=
// (lane>>4)*4+reg, col=n=lane&15. Quaternion components of one token sit in
// 4 adjacent lanes (n%4 = l15%4) -> normalize via __shfl_xor(1,2).
// EPI: 0 = expansion step (delta=tanh, write q+delta | q-delta, width 2*Nreal)
//      1 = quaternion normalize -> fp16 [token][1024]
//      2 = EPI1 + stability-loss accumulation (mean |r|)
//      3 = head: fp32 store to d_out[token*257 + n], n < 257
// ---------------------------------------------------------------------------
template <int EPI>
__global__ __launch_bounds__(256) void gemm_epi(
    const unsigned short* __restrict__ W,
    const unsigned short* __restrict__ Act,
    unsigned short* __restrict__ OutB, float* __restrict__ OutF,
    int K, int Nreal, int ldout) {
  __shared__ unsigned short Wt[128 * 32];
  __shared__ unsigned short At[128 * 32];
  __shared__ float lsum[4];

  const int tid  = threadIdx.x;
  const int wave = tid >> 6;
  const int lane = tid & 63;
  const int l15  = lane & 15;
  const int quad = lane >> 4;
  const int mblock = blockIdx.x * 128;   // token
  const int nblock = blockIdx.y * 128;   // n (output feature)
  const int wn = (wave & 1) * 64;
  const int wm = (wave >> 1) * 64;

  f32x4 acc[4][4];
  const f32x4 zero = {0.f, 0.f, 0.f, 0.f};
#pragma unroll
  for (int a = 0; a < 4; a++)
#pragma unroll
    for (int b = 0; b < 4; b++) acc[a][b] = zero;

  // staging: 512 chunks of 16B per tile; chunk = j*256 + tid;
  // row = chunk>>2 (global row), sub = chunk&3 (16B slice within 64B row)
  const int row0 = tid >> 2;
  const int sub  = tid & 3;
  const unsigned short* gW0 = W   + (size_t)(nblock + row0)      * K + sub * 8;
  const unsigned short* gW1 = W   + (size_t)(nblock + row0 + 64) * K + sub * 8;
  const unsigned short* gA0 = Act + (size_t)(mblock + row0)      * K + sub * 8;
  const unsigned short* gA1 = Act + (size_t)(mblock + row0 + 64) * K + sub * 8;
  unsigned short* lW0 = &Wt[(wave * 64) * 8];
  unsigned short* lW1 = &Wt[(256 + wave * 64) * 8];
  unsigned short* lA0 = &At[(wave * 64) * 8];
  unsigned short* lA1 = &At[(256 + wave * 64) * 8];

  for (int kb = 0; kb < K; kb += 32) {
    GL2LDS16(gW0 + kb, lW0);
    GL2LDS16(gW1 + kb, lW1);
    GL2LDS16(gA0 + kb, lA0);
    GL2LDS16(gA1 + kb, lA1);
    __syncthreads();

    f16x8 afr[4], bfr[4];
#pragma unroll
    for (int ta = 0; ta < 4; ta++)
      afr[ta] = *(const f16x8*)&At[(wm + ta * 16 + l15) * 32 + quad * 8];
#pragma unroll
    for (int tb = 0; tb < 4; tb++)
      bfr[tb] = *(const f16x8*)&Wt[(wn + tb * 16 + l15) * 32 + quad * 8];
#pragma unroll
    for (int ta = 0; ta < 4; ta++)
#pragma unroll
      for (int tb = 0; tb < 4; tb++)
        acc[ta][tb] = __builtin_amdgcn_mfma_f32_16x16x32_f16(
            afr[ta], bfr[tb], acc[ta][tb], 0, 0, 0);
    __syncthreads();
  }

  if constexpr (EPI == 0) {
    // expansion: D row=token, col=n. Old q read + (q±tanh(D)) stores are
    // lane-contiguous along n (32B segments per quad).
#pragma unroll
    for (int ta = 0; ta < 4; ta++) {
      const int tok0 = mblock + wm + ta * 16 + quad * 4;
#pragma unroll
      for (int tb = 0; tb < 4; tb++) {
        const int nb = nblock + wn + tb * 16;
        if (nb < Nreal) {                      // wave-uniform (Nreal %16==0)
          const int n = nb + l15;
          const f32x4 v = acc[ta][tb];
#pragma unroll
          for (int r = 0; r < 4; r++) {
            const int tok = tok0 + r;
            const float iold = h2f(Act[(size_t)tok * K + n]);
            const float d = tanhf(v[r]);
            OutB[(size_t)tok * ldout + n]         = f2h(iold + d);
            OutB[(size_t)tok * ldout + Nreal + n] = f2h(iold - d);
          }
        }
      }
    }
  } else if constexpr (EPI == 1 || EPI == 2) {
    float loss = 0.f;
    const int comp = l15 & 3;   // quaternion component held by this lane
#pragma unroll
    for (int ta = 0; ta < 4; ta++) {
      const int tok0 = mblock + wm + ta * 16 + quad * 4;
#pragma unroll
      for (int tb = 0; tb < 4; tb++) {
        const int n = nblock + wn + tb * 16 + l15;
        const f32x4 v = acc[ta][tb];
#pragma unroll
        for (int r = 0; r < 4; r++) {
          float s = v[r] * v[r];
          s += __shfl_xor(s, 1);
          s += __shfl_xor(s, 2);               // norm^2 across the quaternion
          const float inv = 1.f / (sqrtf(s) + 1e-8f);
          const float o = v[r] * inv;
          OutB[(size_t)(tok0 + r) * ldout + n] = f2h(o);
          if constexpr (EPI == 2)
            if (comp == 0) loss += fabsf(o);
        }
      }
    }
    if constexpr (EPI == 2) {
#pragma unroll
      for (int off = 32; off > 0; off >>= 1) loss += __shfl_down(loss, off);
      if (lane == 0) lsum[wave] = loss;
      __syncthreads();
      if (tid == 0)
        atomicAdd(OutF,
                  (lsum[0] + lsum[1] + lsum[2] + lsum[3]) * (1.f / 8388608.f));
    }
  } else {  // EPI == 3 : head, fp32 stores 64B-coalesced along n
#pragma unroll
    for (int ta = 0; ta < 4; ta++) {
      const int tok0 = mblock + wm + ta * 16 + quad * 4;
#pragma unroll
      for (int tb = 0; tb < 4; tb++) {
        const int n = nblock + wn + tb * 16 + l15;
        if (n < 257) {
          const f32x4 v = acc[ta][tb];
#pragma unroll
          for (int r = 0; r < 4; r++)
            OutF[(size_t)(tok0 + r) * 257 + n] = v[r];
        }
      }
    }
  }
}

// ---------------------------------------------------------------------------
extern "C" void kernel_launch(void* const* d_in, const int* in_sizes, int n_in,
                              void* d_out, int out_size, void* d_ws,
                              size_t ws_size, hipStream_t stream) {
  const int*   x    = (const int*)d_in[0];
  const float* emb  = (const float*)d_in[1];
  const float* we0  = (const float*)d_in[2];
  const float* we1  = (const float*)d_in[3];
  const float* we2  = (const float*)d_in[4];
  const float* we3  = (const float*)d_in[5];
  const float* we4  = (const float*)d_in[6];
  const float* we5  = (const float*)d_in[7];
  const float* we6  = (const float*)d_in[8];
  const float* we7  = (const float*)d_in[9];
  const float* wlay = (const float*)d_in[10];
  const float* wh   = (const float*)d_in[11];
  float* out = (float*)d_out;

  // workspace layout (~142 MiB)
  char* p = (char*)d_ws;
  auto alloc = [&](size_t bytes) {
    void* r = (void*)p;
    p += (bytes + 255) & ~(size_t)255;
    return r;
  };
  unsigned short* act0 = (unsigned short*)alloc(32768ull * 1024 * 2);
  unsigned short* act1 = (unsigned short*)alloc(32768ull * 1024 * 2);
  unsigned short* E4 = (unsigned short*)alloc(128 * 64 * 2);
  unsigned short* E5 = (unsigned short*)alloc(128 * 128 * 2);
  unsigned short* E6 = (unsigned short*)alloc(256 * 256 * 2);
  unsigned short* E7 = (unsigned short*)alloc(512 * 512 * 2);
  unsigned short* EL = (unsigned short*)alloc(6ull * 1024 * 1024 * 2);
  unsigned short* WH = (unsigned short*)alloc(384 * 1024 * 2);

  // zero the stability-loss slot (d_out is poisoned before every launch)
  hipMemsetAsync(out + 8421376, 0, 4, stream);

  // weight expansion (Hamilton blocks -> real fp16 matrices)
  expand_ham<<<dim3(8192 / 256), 256, 0, stream>>>(we4, E4, 16, 6, 128 * 64);
  expand_ham<<<dim3(16384 / 256), 256, 0, stream>>>(we5, E5, 32, 7, 128 * 128);
  expand_ham<<<dim3(65536 / 256), 256, 0, stream>>>(we6, E6, 64, 8, 256 * 256);
  expand_ham<<<dim3(262144 / 256), 256, 0, stream>>>(we7, E7, 128, 9,
                                                     512 * 512);
  for (int d = 0; d < 6; d++)
    expand_ham<<<dim3(1048576 / 256), 256, 0, stream>>>(
        wlay + (size_t)d * 262144, EL + (size_t)d * 1048576, 256, 10, 1048576);
  conv_head<<<dim3(384 * 1024 / 256), 256, 0, stream>>>(wh, WH);

  // embed + expansion steps 0..3 -> act0 [32768][64] fp16
  embed_expand<<<dim3(128), 256, 0, stream>>>(x, emb, we0, we1, we2, we3, act0);

  // expansion steps 4..7 as fused GEMMs
  gemm_epi<0><<<dim3(256, 1), 256, 0, stream>>>(E4, act0, act1, nullptr, 64,
                                                64, 128);
  gemm_epi<0><<<dim3(256, 1), 256, 0, stream>>>(E5, act1, act0, nullptr, 128,
                                                128, 256);
  gemm_epi<0><<<dim3(256, 2), 256, 0, stream>>>(E6, act0, act1, nullptr, 256,
                                                256, 512);
  gemm_epi<0><<<dim3(256, 4), 256, 0, stream>>>(E7, act1, act0, nullptr, 512,
                                                512, 1024);

  // 6 quaternion-linear + normalize layers (last also accumulates loss)
  unsigned short* a = act0;
  unsigned short* b = act1;
  for (int d = 0; d < 5; d++) {
    gemm_epi<1><<<dim3(256, 8), 256, 0, stream>>>(EL + (size_t)d * 1048576, a,
                                                  b, nullptr, 1024, 1024, 1024);
    unsigned short* t = a; a = b; b = t;
  }
  gemm_epi<2><<<dim3(256, 8), 256, 0, stream>>>(EL + 5ull * 1048576, a, b,
                                                out + 8421376, 1024, 1024,
                                                1024);
  { unsigned short* t = a; a = b; b = t; }

  // head: logits = h @ w_head^T  (N padded 257 -> 384, masked stores)
  gemm_epi<3><<<dim3(256, 3), 256, 0, stream>>>(WH, a, nullptr, out, 1024, 257,
                                                0);
}

// Round 4
// 879.048 us; speedup vs baseline: 1.2802x; 1.2802x over previous
//
#include <hip/hip_runtime.h>

// ---------------------------------------------------------------------------
// H2Q knot kernel: embed -> 8 doubling quaternion expansion steps ->
// 6 quaternion-linear+normalize layers -> vocab head (+ stability loss).
// Strategy: expand Hamilton-product weights into real FP16 matrices, run all
// wide steps as MFMA GEMMs (128x128 tile, 16x16x32 f16, global_load_lds
// width-16 staging) with fused epilogues.
// R4: revert to R2 operand order (D row=n, col=token: lane owns a whole
// quaternion -> register-local normalize; R3's n-major epilogue quadrupled
// VALU work and regressed). Primary change: BK=64 K-loop -- two 32-k
// sub-tiles in 4 separate 8KB LDS regions, one barrier pair per 64 k
// (halves the vmcnt(0)+barrier drains that dominate at K=1024).
// Secondary: grid x=n-tile (fastest) so co-resident blocks share Act tile
// and keep the 2MB W L2-hot.
// ---------------------------------------------------------------------------

typedef _Float16 f16x8 __attribute__((ext_vector_type(8)));
typedef float    f32x4 __attribute__((ext_vector_type(4)));

#define GL2LDS16(gp, lp) __builtin_amdgcn_global_load_lds(                     \
    (const __attribute__((address_space(1))) void*)(gp),                       \
    (__attribute__((address_space(3))) void*)(lp), 16, 0, 0)

__device__ __forceinline__ unsigned short f2h(float f) {
  union { _Float16 h; unsigned short u; } c;
  c.h = (_Float16)f;                       // RNE
  return c.u;
}
__device__ __forceinline__ float h2f(unsigned short u) {
  union { unsigned short u; _Float16 h; } c;
  c.u = u;
  return (float)c.h;
}

// ---------------------------------------------------------------------------
// Weight expansion: quaternion weights [4][cq][cq] -> real fp16 matrix
// E[n][k], n=4o+a (out), k=4i+b (in), rows >= 4cq zero-padded.
// ---------------------------------------------------------------------------
__global__ __launch_bounds__(256) void expand_ham(
    const float* __restrict__ w, unsigned short* __restrict__ out,
    int cq, int kbits, int total) {
  int id = blockIdx.x * 256 + threadIdx.x;
  if (id >= total) return;
  const int K = 1 << kbits;
  const int n = id >> kbits;
  const int k = id & (K - 1);
  float val = 0.f;
  if (n < 4 * cq) {
    const int o = n >> 2, a = n & 3, i = k >> 2, b = k & 3;
    const int   comp[4][4] = {{0,1,2,3},{1,0,3,2},{2,3,0,1},{3,2,1,0}};
    const float sgn [4][4] = {{1.f,-1.f,-1.f,-1.f},{1.f,1.f,1.f,-1.f},
                              {1.f,-1.f,1.f,1.f},{1.f,1.f,-1.f,1.f}};
    val = sgn[a][b] * w[comp[a][b] * cq * cq + o * cq + i];
  }
  out[id] = f2h(val);
}

__global__ __launch_bounds__(256) void conv_head(
    const float* __restrict__ wh, unsigned short* __restrict__ out) {
  int id = blockIdx.x * 256 + threadIdx.x;   // 384*1024 threads
  int v = id >> 10, k = id & 1023;
  out[id] = f2h(v < 257 ? wh[v * 1024 + k] : 0.f);
}

// ---------------------------------------------------------------------------
// Embed + expansion steps 0..3 (cq=1,2,4,8), one token per thread (weights are
// wave-uniform -> scalar-cached broadcast loads). Output: fp16 [32768][64].
// ---------------------------------------------------------------------------
template <int CQ>
__device__ __forceinline__ void exp_step(float (&q)[16][4],
                                         const float* __restrict__ w) {
  float d[CQ][4];
#pragma unroll
  for (int o = 0; o < CQ; o++) {
    float pr = 0.f, pi = 0.f, pj = 0.f, pk = 0.f;
#pragma unroll
    for (int i = 0; i < CQ; i++) {
      const float wr = w[0 * CQ * CQ + o * CQ + i];
      const float wi = w[1 * CQ * CQ + o * CQ + i];
      const float wj = w[2 * CQ * CQ + o * CQ + i];
      const float wk = w[3 * CQ * CQ + o * CQ + i];
      const float qr = q[i][0], qi = q[i][1], qj = q[i][2], qk = q[i][3];
      pr += wr * qr - wi * qi - wj * qj - wk * qk;
      pi += wi * qr + wr * qi + wk * qj - wj * qk;
      pj += wj * qr - wk * qi + wr * qj + wi * qk;
      pk += wk * qr + wj * qi - wi * qj + wr * qk;
    }
    d[o][0] = tanhf(pr); d[o][1] = tanhf(pi);
    d[o][2] = tanhf(pj); d[o][3] = tanhf(pk);
  }
#pragma unroll
  for (int o = 0; o < CQ; o++)
#pragma unroll
    for (int a = 0; a < 4; a++) {
      const float dd = d[o][a], qq = q[o][a];
      q[o][a]      = qq + dd;
      q[CQ + o][a] = qq - dd;
    }
}

__global__ __launch_bounds__(256) void embed_expand(
    const int* __restrict__ x, const float* __restrict__ emb,
    const float* __restrict__ w0, const float* __restrict__ w1,
    const float* __restrict__ w2, const float* __restrict__ w3,
    unsigned short* __restrict__ out) {
  const int t = blockIdx.x * 256 + threadIdx.x;  // 32768 tokens
  float q[16][4];
  const int v = x[t];
  const float4 e = *(const float4*)(emb + v * 4);
  q[0][0] = e.x; q[0][1] = e.y; q[0][2] = e.z; q[0][3] = e.w;
  exp_step<1>(q, w0);
  exp_step<2>(q, w1);
  exp_step<4>(q, w2);
  exp_step<8>(q, w3);
  ushort4* o4 = (ushort4*)(out + (size_t)t * 64);
#pragma unroll
  for (int c = 0; c < 16; c++) {
    ushort4 u;
    u.x = f2h(q[c][0]); u.y = f2h(q[c][1]);
    u.z = f2h(q[c][2]); u.w = f2h(q[c][3]);
    o4[c] = u;
  }
}

// ---------------------------------------------------------------------------
// Fused GEMM: D[n][token] = sum_k W[n][k] * Act[token][k] (both fp16,
// k-contiguous). Grid: x = n-tile (fastest, for L2 sharing), y = token-tile.
// 128x128 block tile, 4 waves each 64x64 (4x4 of 16x16x32 MFMA, A=W, B=Act).
// C/D: col=token=lane&15, row=n=(lane>>4)*4+reg -> each lane's 4 acc values
// are one quaternion (register-local normalize).
// BK=64: two 32-k sub-tiles (L/H) in separate 8KB LDS regions; one barrier
// pair per 64 k.
// EPI: 0 = expansion step (delta=tanh, write q+delta | q-delta, width 2*Nreal)
//      1 = quaternion normalize -> fp16 [token][1024]
//      2 = EPI1 + stability-loss accumulation (mean |r|)
//      3 = head: fp32 store to d_out[token*257 + n], n < 257
// ---------------------------------------------------------------------------
template <int EPI>
__global__ __launch_bounds__(256) void gemm_epi(
    const unsigned short* __restrict__ W,
    const unsigned short* __restrict__ Act,
    unsigned short* __restrict__ OutB, float* __restrict__ OutF,
    int K, int Nreal, int ldout) {
  __shared__ unsigned short WtL[128 * 32];
  __shared__ unsigned short WtH[128 * 32];
  __shared__ unsigned short AtL[128 * 32];
  __shared__ unsigned short AtH[128 * 32];
  __shared__ float lsum[4];

  const int tid  = threadIdx.x;
  const int wave = tid >> 6;
  const int lane = tid & 63;
  const int l15  = lane & 15;
  const int quad = lane >> 4;
  const int nblock = blockIdx.x * 128;   // n (output feature)
  const int mblock = blockIdx.y * 128;   // token
  const int wn = (wave & 1) * 64;
  const int wm = (wave >> 1) * 64;

  f32x4 acc[4][4];
  const f32x4 zero = {0.f, 0.f, 0.f, 0.f};
#pragma unroll
  for (int a = 0; a < 4; a++)
#pragma unroll
    for (int b = 0; b < 4; b++) acc[a][b] = zero;

  // staging: per 32-k sub-tile, 2 call-sites x 4 waves x 1KB = 8KB;
  // lane chunk: row = tid>>2 (global row), sub = tid&3 (16B slice of 64B row)
  const int row0 = tid >> 2;
  const int sub  = tid & 3;
  const unsigned short* gW0 = W   + (size_t)(nblock + row0)      * K + sub * 8;
  const unsigned short* gW1 = W   + (size_t)(nblock + row0 + 64) * K + sub * 8;
  const unsigned short* gA0 = Act + (size_t)(mblock + row0)      * K + sub * 8;
  const unsigned short* gA1 = Act + (size_t)(mblock + row0 + 64) * K + sub * 8;
  unsigned short* lWL0 = &WtL[wave * 512];
  unsigned short* lWL1 = &WtL[2048 + wave * 512];
  unsigned short* lWH0 = &WtH[wave * 512];
  unsigned short* lWH1 = &WtH[2048 + wave * 512];
  unsigned short* lAL0 = &AtL[wave * 512];
  unsigned short* lAL1 = &AtL[2048 + wave * 512];
  unsigned short* lAH0 = &AtH[wave * 512];
  unsigned short* lAH1 = &AtH[2048 + wave * 512];

  for (int kb = 0; kb < K; kb += 64) {
    GL2LDS16(gW0 + kb,      lWL0);
    GL2LDS16(gW1 + kb,      lWL1);
    GL2LDS16(gW0 + kb + 32, lWH0);
    GL2LDS16(gW1 + kb + 32, lWH1);
    GL2LDS16(gA0 + kb,      lAL0);
    GL2LDS16(gA1 + kb,      lAL1);
    GL2LDS16(gA0 + kb + 32, lAH0);
    GL2LDS16(gA1 + kb + 32, lAH1);
    __syncthreads();

    {
      f16x8 afr[4], bfr[4];
#pragma unroll
      for (int tn = 0; tn < 4; tn++)
        afr[tn] = *(const f16x8*)&WtL[(wn + tn * 16 + l15) * 32 + quad * 8];
#pragma unroll
      for (int tm = 0; tm < 4; tm++)
        bfr[tm] = *(const f16x8*)&AtL[(wm + tm * 16 + l15) * 32 + quad * 8];
#pragma unroll
      for (int tn = 0; tn < 4; tn++)
#pragma unroll
        for (int tm = 0; tm < 4; tm++)
          acc[tn][tm] = __builtin_amdgcn_mfma_f32_16x16x32_f16(
              afr[tn], bfr[tm], acc[tn][tm], 0, 0, 0);
    }
    {
      f16x8 afr[4], bfr[4];
#pragma unroll
      for (int tn = 0; tn < 4; tn++)
        afr[tn] = *(const f16x8*)&WtH[(wn + tn * 16 + l15) * 32 + quad * 8];
#pragma unroll
      for (int tm = 0; tm < 4; tm++)
        bfr[tm] = *(const f16x8*)&AtH[(wm + tm * 16 + l15) * 32 + quad * 8];
#pragma unroll
      for (int tn = 0; tn < 4; tn++)
#pragma unroll
        for (int tm = 0; tm < 4; tm++)
          acc[tn][tm] = __builtin_amdgcn_mfma_f32_16x16x32_f16(
              afr[tn], bfr[tm], acc[tn][tm], 0, 0, 0);
    }
    __syncthreads();
  }

  if constexpr (EPI == 0) {
#pragma unroll
    for (int tn = 0; tn < 4; tn++) {
      const int n = nblock + wn + tn * 16 + quad * 4;
      if (n < Nreal) {
#pragma unroll
        for (int tm = 0; tm < 4; tm++) {
          const int token = mblock + wm + tm * 16 + l15;
          const f32x4 v = acc[tn][tm];
          const unsigned short* ip = Act + (size_t)token * K + n;
          const float i0 = h2f(ip[0]), i1 = h2f(ip[1]);
          const float i2 = h2f(ip[2]), i3 = h2f(ip[3]);
          const float d0 = tanhf(v[0]), d1 = tanhf(v[1]);
          const float d2 = tanhf(v[2]), d3 = tanhf(v[3]);
          ushort4 up, um;
          up.x = f2h(i0 + d0); up.y = f2h(i1 + d1);
          up.z = f2h(i2 + d2); up.w = f2h(i3 + d3);
          um.x = f2h(i0 - d0); um.y = f2h(i1 - d1);
          um.z = f2h(i2 - d2); um.w = f2h(i3 - d3);
          *(ushort4*)&OutB[(size_t)token * ldout + n] = up;
          *(ushort4*)&OutB[(size_t)token * ldout + Nreal + n] = um;
        }
      }
    }
  } else if constexpr (EPI == 1 || EPI == 2) {
    float loss = 0.f;
#pragma unroll
    for (int tn = 0; tn < 4; tn++) {
      const int n = nblock + wn + tn * 16 + quad * 4;
#pragma unroll
      for (int tm = 0; tm < 4; tm++) {
        const int token = mblock + wm + tm * 16 + l15;
        const f32x4 v = acc[tn][tm];
        const float nrm =
            sqrtf(v[0] * v[0] + v[1] * v[1] + v[2] * v[2] + v[3] * v[3]);
        const float inv = 1.f / (nrm + 1e-8f);
        ushort4 u;
        u.x = f2h(v[0] * inv); u.y = f2h(v[1] * inv);
        u.z = f2h(v[2] * inv); u.w = f2h(v[3] * inv);
        *(ushort4*)&OutB[(size_t)token * ldout + n] = u;
        if constexpr (EPI == 2) loss += fabsf(v[0] * inv);
      }
    }
    if constexpr (EPI == 2) {
#pragma unroll
      for (int off = 32; off > 0; off >>= 1) loss += __shfl_down(loss, off);
      if (lane == 0) lsum[wave] = loss;
      __syncthreads();
      if (tid == 0)
        atomicAdd(OutF,
                  (lsum[0] + lsum[1] + lsum[2] + lsum[3]) * (1.f / 8388608.f));
    }
  } else {  // EPI == 3 : head
#pragma unroll
    for (int tn = 0; tn < 4; tn++) {
      const int n = nblock + wn + tn * 16 + quad * 4;
      if (n < 257) {
#pragma unroll
        for (int tm = 0; tm < 4; tm++) {
          const int token = mblock + wm + tm * 16 + l15;
          const f32x4 v = acc[tn][tm];
#pragma unroll
          for (int r = 0; r < 4; r++)
            if (n + r < 257) OutF[(size_t)token * 257 + n + r] = v[r];
        }
      }
    }
  }
}

// ---------------------------------------------------------------------------
extern "C" void kernel_launch(void* const* d_in, const int* in_sizes, int n_in,
                              void* d_out, int out_size, void* d_ws,
                              size_t ws_size, hipStream_t stream) {
  const int*   x    = (const int*)d_in[0];
  const float* emb  = (const float*)d_in[1];
  const float* we0  = (const float*)d_in[2];
  const float* we1  = (const float*)d_in[3];
  const float* we2  = (const float*)d_in[4];
  const float* we3  = (const float*)d_in[5];
  const float* we4  = (const float*)d_in[6];
  const float* we5  = (const float*)d_in[7];
  const float* we6  = (const float*)d_in[8];
  const float* we7  = (const float*)d_in[9];
  const float* wlay = (const float*)d_in[10];
  const float* wh   = (const float*)d_in[11];
  float* out = (float*)d_out;

  // workspace layout (~142 MiB)
  char* p = (char*)d_ws;
  auto alloc = [&](size_t bytes) {
    void* r = (void*)p;
    p += (bytes + 255) & ~(size_t)255;
    return r;
  };
  unsigned short* act0 = (unsigned short*)alloc(32768ull * 1024 * 2);
  unsigned short* act1 = (unsigned short*)alloc(32768ull * 1024 * 2);
  unsigned short* E4 = (unsigned short*)alloc(128 * 64 * 2);
  unsigned short* E5 = (unsigned short*)alloc(128 * 128 * 2);
  unsigned short* E6 = (unsigned short*)alloc(256 * 256 * 2);
  unsigned short* E7 = (unsigned short*)alloc(512 * 512 * 2);
  unsigned short* EL = (unsigned short*)alloc(6ull * 1024 * 1024 * 2);
  unsigned short* WH = (unsigned short*)alloc(384 * 1024 * 2);

  // zero the stability-loss slot (d_out is poisoned before every launch)
  hipMemsetAsync(out + 8421376, 0, 4, stream);

  // weight expansion (Hamilton blocks -> real fp16 matrices)
  expand_ham<<<dim3(8192 / 256), 256, 0, stream>>>(we4, E4, 16, 6, 128 * 64);
  expand_ham<<<dim3(16384 / 256), 256, 0, stream>>>(we5, E5, 32, 7, 128 * 128);
  expand_ham<<<dim3(65536 / 256), 256, 0, stream>>>(we6, E6, 64, 8, 256 * 256);
  expand_ham<<<dim3(262144 / 256), 256, 0, stream>>>(we7, E7, 128, 9,
                                                     512 * 512);
  for (int d = 0; d < 6; d++)
    expand_ham<<<dim3(1048576 / 256), 256, 0, stream>>>(
        wlay + (size_t)d * 262144, EL + (size_t)d * 1048576, 256, 10, 1048576);
  conv_head<<<dim3(384 * 1024 / 256), 256, 0, stream>>>(wh, WH);

  // embed + expansion steps 0..3 -> act0 [32768][64] fp16
  embed_expand<<<dim3(128), 256, 0, stream>>>(x, emb, we0, we1, we2, we3, act0);

  // expansion steps 4..7 as fused GEMMs (grid x = n-tiles, y = token-tiles)
  gemm_epi<0><<<dim3(1, 256), 256, 0, stream>>>(E4, act0, act1, nullptr, 64,
                                                64, 128);
  gemm_epi<0><<<dim3(1, 256), 256, 0, stream>>>(E5, act1, act0, nullptr, 128,
                                                128, 256);
  gemm_epi<0><<<dim3(2, 256), 256, 0, stream>>>(E6, act0, act1, nullptr, 256,
                                                256, 512);
  gemm_epi<0><<<dim3(4, 256), 256, 0, stream>>>(E7, act1, act0, nullptr, 512,
                                                512, 1024);

  // 6 quaternion-linear + normalize layers (last also accumulates loss)
  unsigned short* a = act0;
  unsigned short* b = act1;
  for (int d = 0; d < 5; d++) {
    gemm_epi<1><<<dim3(8, 256), 256, 0, stream>>>(EL + (size_t)d * 1048576, a,
                                                  b, nullptr, 1024, 1024, 1024);
    unsigned short* t = a; a = b; b = t;
  }
  gemm_epi<2><<<dim3(8, 256), 256, 0, stream>>>(EL + 5ull * 1048576, a, b,
                                                out + 8421376, 1024, 1024,
                                                1024);
  { unsigned short* t = a; a = b; b = t; }

  // head: logits = h @ w_head^T  (N padded 257 -> 384, masked stores)
  gemm_epi<3><<<dim3(3, 256), 256, 0, stream>>>(WH, a, nullptr, out, 1024, 257,
                                                0);
}

// Round 5
// 865.566 us; speedup vs baseline: 1.3002x; 1.0156x over previous
//
#include <hip/hip_runtime.h>

// ---------------------------------------------------------------------------
// H2Q knot kernel: embed -> 8 doubling quaternion expansion steps ->
// 6 quaternion-linear+normalize layers -> vocab head (+ stability loss).
// Strategy: expand Hamilton-product weights into real FP16 matrices, run all
// wide steps as MFMA GEMMs (128x128 tile, BK=64, 16x16x32 f16,
// global_load_lds width-16 staging) with fused epilogues.
// R5: XCD-aware block swizzle. R4's n-fastest grid put the 8 blocks sharing
// an Act tile on 8 different XCDs (private L2s -> 4x Act over-fetch,
// FETCH 265MB vs 69MB ideal). Remap: xcd=L%8 owns token-tiles
// [32*xcd, 32*xcd+32), iterating n-tiles fastest -> per-XCD working set
// ~2MB Act + 2MB W = one L2. Act fetched once chip-wide, W once per XCD.
// ---------------------------------------------------------------------------

typedef _Float16 f16x8 __attribute__((ext_vector_type(8)));
typedef float    f32x4 __attribute__((ext_vector_type(4)));

#define GL2LDS16(gp, lp) __builtin_amdgcn_global_load_lds(                     \
    (const __attribute__((address_space(1))) void*)(gp),                       \
    (__attribute__((address_space(3))) void*)(lp), 16, 0, 0)

__device__ __forceinline__ unsigned short f2h(float f) {
  union { _Float16 h; unsigned short u; } c;
  c.h = (_Float16)f;                       // RNE
  return c.u;
}
__device__ __forceinline__ float h2f(unsigned short u) {
  union { unsigned short u; _Float16 h; } c;
  c.u = u;
  return (float)c.h;
}

// ---------------------------------------------------------------------------
// Weight expansion: quaternion weights [4][cq][cq] -> real fp16 matrix
// E[n][k], n=4o+a (out), k=4i+b (in), rows >= 4cq zero-padded.
// ---------------------------------------------------------------------------
__global__ __launch_bounds__(256) void expand_ham(
    const float* __restrict__ w, unsigned short* __restrict__ out,
    int cq, int kbits, int total) {
  int id = blockIdx.x * 256 + threadIdx.x;
  if (id >= total) return;
  const int K = 1 << kbits;
  const int n = id >> kbits;
  const int k = id & (K - 1);
  float val = 0.f;
  if (n < 4 * cq) {
    const int o = n >> 2, a = n & 3, i = k >> 2, b = k & 3;
    const int   comp[4][4] = {{0,1,2,3},{1,0,3,2},{2,3,0,1},{3,2,1,0}};
    const float sgn [4][4] = {{1.f,-1.f,-1.f,-1.f},{1.f,1.f,1.f,-1.f},
                              {1.f,-1.f,1.f,1.f},{1.f,1.f,-1.f,1.f}};
    val = sgn[a][b] * w[comp[a][b] * cq * cq + o * cq + i];
  }
  out[id] = f2h(val);
}

__global__ __launch_bounds__(256) void conv_head(
    const float* __restrict__ wh, unsigned short* __restrict__ out) {
  int id = blockIdx.x * 256 + threadIdx.x;   // 384*1024 threads
  int v = id >> 10, k = id & 1023;
  out[id] = f2h(v < 257 ? wh[v * 1024 + k] : 0.f);
}

// ---------------------------------------------------------------------------
// Embed + expansion steps 0..3 (cq=1,2,4,8), one token per thread (weights are
// wave-uniform -> scalar-cached broadcast loads). Output: fp16 [32768][64].
// ---------------------------------------------------------------------------
template <int CQ>
__device__ __forceinline__ void exp_step(float (&q)[16][4],
                                         const float* __restrict__ w) {
  float d[CQ][4];
#pragma unroll
  for (int o = 0; o < CQ; o++) {
    float pr = 0.f, pi = 0.f, pj = 0.f, pk = 0.f;
#pragma unroll
    for (int i = 0; i < CQ; i++) {
      const float wr = w[0 * CQ * CQ + o * CQ + i];
      const float wi = w[1 * CQ * CQ + o * CQ + i];
      const float wj = w[2 * CQ * CQ + o * CQ + i];
      const float wk = w[3 * CQ * CQ + o * CQ + i];
      const float qr = q[i][0], qi = q[i][1], qj = q[i][2], qk = q[i][3];
      pr += wr * qr - wi * qi - wj * qj - wk * qk;
      pi += wi * qr + wr * qi + wk * qj - wj * qk;
      pj += wj * qr - wk * qi + wr * qj + wi * qk;
      pk += wk * qr + wj * qi - wi * qj + wr * qk;
    }
    d[o][0] = tanhf(pr); d[o][1] = tanhf(pi);
    d[o][2] = tanhf(pj); d[o][3] = tanhf(pk);
  }
#pragma unroll
  for (int o = 0; o < CQ; o++)
#pragma unroll
    for (int a = 0; a < 4; a++) {
      const float dd = d[o][a], qq = q[o][a];
      q[o][a]      = qq + dd;
      q[CQ + o][a] = qq - dd;
    }
}

__global__ __launch_bounds__(256) void embed_expand(
    const int* __restrict__ x, const float* __restrict__ emb,
    const float* __restrict__ w0, const float* __restrict__ w1,
    const float* __restrict__ w2, const float* __restrict__ w3,
    unsigned short* __restrict__ out) {
  const int t = blockIdx.x * 256 + threadIdx.x;  // 32768 tokens
  float q[16][4];
  const int v = x[t];
  const float4 e = *(const float4*)(emb + v * 4);
  q[0][0] = e.x; q[0][1] = e.y; q[0][2] = e.z; q[0][3] = e.w;
  exp_step<1>(q, w0);
  exp_step<2>(q, w1);
  exp_step<4>(q, w2);
  exp_step<8>(q, w3);
  ushort4* o4 = (ushort4*)(out + (size_t)t * 64);
#pragma unroll
  for (int c = 0; c < 16; c++) {
    ushort4 u;
    u.x = f2h(q[c][0]); u.y = f2h(q[c][1]);
    u.z = f2h(q[c][2]); u.w = f2h(q[c][3]);
    o4[c] = u;
  }
}

// ---------------------------------------------------------------------------
// Fused GEMM: D[n][token] = sum_k W[n][k] * Act[token][k] (both fp16,
// k-contiguous). Grid: gridDim.x = #n-tiles, gridDim.y = 256 token-tiles;
// in-kernel XCD swizzle (see header). 128x128 block tile, 4 waves each 64x64
// (4x4 of 16x16x32 MFMA, A=W, B=Act). C/D: col=token=lane&15,
// row=n=(lane>>4)*4+reg -> each lane's 4 acc values are one quaternion.
// BK=64: two 32-k sub-tiles (L/H) in separate 8KB LDS regions; one barrier
// pair per 64 k.
// EPI: 0 = expansion step (delta=tanh, write q+delta | q-delta, width 2*Nreal)
//      1 = quaternion normalize -> fp16 [token][1024]
//      2 = EPI1 + stability-loss accumulation (mean |r|)
//      3 = head: fp32 store to d_out[token*257 + n], n < 257
// ---------------------------------------------------------------------------
template <int EPI>
__global__ __launch_bounds__(256) void gemm_epi(
    const unsigned short* __restrict__ W,
    const unsigned short* __restrict__ Act,
    unsigned short* __restrict__ OutB, float* __restrict__ OutF,
    int K, int Nreal, int ldout) {
  __shared__ unsigned short WtL[128 * 32];
  __shared__ unsigned short WtH[128 * 32];
  __shared__ unsigned short AtL[128 * 32];
  __shared__ unsigned short AtH[128 * 32];
  __shared__ float lsum[4];

  const int tid  = threadIdx.x;
  const int wave = tid >> 6;
  const int lane = tid & 63;
  const int l15  = lane & 15;
  const int quad = lane >> 4;

  // XCD-aware swizzle: dispatch linear L (x fastest) -> XCD = L%8 (round-
  // robin heuristic). XCD j owns token-tiles [32j, 32j+32), n fastest.
  const int Gx = gridDim.x;
  const int L  = blockIdx.y * Gx + blockIdx.x;
  const int j  = L & 7;
  const int s  = L >> 3;
  const int nblock = (s % Gx) * 128;               // n (output feature)
  const int mblock = (32 * j + s / Gx) * 128;      // token
  const int wn = (wave & 1) * 64;
  const int wm = (wave >> 1) * 64;

  f32x4 acc[4][4];
  const f32x4 zero = {0.f, 0.f, 0.f, 0.f};
#pragma unroll
  for (int a = 0; a < 4; a++)
#pragma unroll
    for (int b = 0; b < 4; b++) acc[a][b] = zero;

  // staging: per 32-k sub-tile, 2 call-sites x 4 waves x 1KB = 8KB;
  // lane chunk: row = tid>>2 (global row), sub = tid&3 (16B slice of 64B row)
  const int row0 = tid >> 2;
  const int sub  = tid & 3;
  const unsigned short* gW0 = W   + (size_t)(nblock + row0)      * K + sub * 8;
  const unsigned short* gW1 = W   + (size_t)(nblock + row0 + 64) * K + sub * 8;
  const unsigned short* gA0 = Act + (size_t)(mblock + row0)      * K + sub * 8;
  const unsigned short* gA1 = Act + (size_t)(mblock + row0 + 64) * K + sub * 8;
  unsigned short* lWL0 = &WtL[wave * 512];
  unsigned short* lWL1 = &WtL[2048 + wave * 512];
  unsigned short* lWH0 = &WtH[wave * 512];
  unsigned short* lWH1 = &WtH[2048 + wave * 512];
  unsigned short* lAL0 = &AtL[wave * 512];
  unsigned short* lAL1 = &AtL[2048 + wave * 512];
  unsigned short* lAH0 = &AtH[wave * 512];
  unsigned short* lAH1 = &AtH[2048 + wave * 512];

  for (int kb = 0; kb < K; kb += 64) {
    GL2LDS16(gW0 + kb,      lWL0);
    GL2LDS16(gW1 + kb,      lWL1);
    GL2LDS16(gW0 + kb + 32, lWH0);
    GL2LDS16(gW1 + kb + 32, lWH1);
    GL2LDS16(gA0 + kb,      lAL0);
    GL2LDS16(gA1 + kb,      lAL1);
    GL2LDS16(gA0 + kb + 32, lAH0);
    GL2LDS16(gA1 + kb + 32, lAH1);
    __syncthreads();

    {
      f16x8 afr[4], bfr[4];
#pragma unroll
      for (int tn = 0; tn < 4; tn++)
        afr[tn] = *(const f16x8*)&WtL[(wn + tn * 16 + l15) * 32 + quad * 8];
#pragma unroll
      for (int tm = 0; tm < 4; tm++)
        bfr[tm] = *(const f16x8*)&AtL[(wm + tm * 16 + l15) * 32 + quad * 8];
#pragma unroll
      for (int tn = 0; tn < 4; tn++)
#pragma unroll
        for (int tm = 0; tm < 4; tm++)
          acc[tn][tm] = __builtin_amdgcn_mfma_f32_16x16x32_f16(
              afr[tn], bfr[tm], acc[tn][tm], 0, 0, 0);
    }
    {
      f16x8 afr[4], bfr[4];
#pragma unroll
      for (int tn = 0; tn < 4; tn++)
        afr[tn] = *(const f16x8*)&WtH[(wn + tn * 16 + l15) * 32 + quad * 8];
#pragma unroll
      for (int tm = 0; tm < 4; tm++)
        bfr[tm] = *(const f16x8*)&AtH[(wm + tm * 16 + l15) * 32 + quad * 8];
#pragma unroll
      for (int tn = 0; tn < 4; tn++)
#pragma unroll
        for (int tm = 0; tm < 4; tm++)
          acc[tn][tm] = __builtin_amdgcn_mfma_f32_16x16x32_f16(
              afr[tn], bfr[tm], acc[tn][tm], 0, 0, 0);
    }
    __syncthreads();
  }

  if constexpr (EPI == 0) {
#pragma unroll
    for (int tn = 0; tn < 4; tn++) {
      const int n = nblock + wn + tn * 16 + quad * 4;
      if (n < Nreal) {
#pragma unroll
        for (int tm = 0; tm < 4; tm++) {
          const int token = mblock + wm + tm * 16 + l15;
          const f32x4 v = acc[tn][tm];
          const unsigned short* ip = Act + (size_t)token * K + n;
          const float i0 = h2f(ip[0]), i1 = h2f(ip[1]);
          const float i2 = h2f(ip[2]), i3 = h2f(ip[3]);
          const float d0 = tanhf(v[0]), d1 = tanhf(v[1]);
          const float d2 = tanhf(v[2]), d3 = tanhf(v[3]);
          ushort4 up, um;
          up.x = f2h(i0 + d0); up.y = f2h(i1 + d1);
          up.z = f2h(i2 + d2); up.w = f2h(i3 + d3);
          um.x = f2h(i0 - d0); um.y = f2h(i1 - d1);
          um.z = f2h(i2 - d2); um.w = f2h(i3 - d3);
          *(ushort4*)&OutB[(size_t)token * ldout + n] = up;
          *(ushort4*)&OutB[(size_t)token * ldout + Nreal + n] = um;
        }
      }
    }
  } else if constexpr (EPI == 1 || EPI == 2) {
    float loss = 0.f;
#pragma unroll
    for (int tn = 0; tn < 4; tn++) {
      const int n = nblock + wn + tn * 16 + quad * 4;
#pragma unroll
      for (int tm = 0; tm < 4; tm++) {
        const int token = mblock + wm + tm * 16 + l15;
        const f32x4 v = acc[tn][tm];
        const float nrm =
            sqrtf(v[0] * v[0] + v[1] * v[1] + v[2] * v[2] + v[3] * v[3]);
        const float inv = 1.f / (nrm + 1e-8f);
        ushort4 u;
        u.x = f2h(v[0] * inv); u.y = f2h(v[1] * inv);
        u.z = f2h(v[2] * inv); u.w = f2h(v[3] * inv);
        *(ushort4*)&OutB[(size_t)token * ldout + n] = u;
        if constexpr (EPI == 2) loss += fabsf(v[0] * inv);
      }
    }
    if constexpr (EPI == 2) {
#pragma unroll
      for (int off = 32; off > 0; off >>= 1) loss += __shfl_down(loss, off);
      if (lane == 0) lsum[wave] = loss;
      __syncthreads();
      if (tid == 0)
        atomicAdd(OutF,
                  (lsum[0] + lsum[1] + lsum[2] + lsum[3]) * (1.f / 8388608.f));
    }
  } else {  // EPI == 3 : head
#pragma unroll
    for (int tn = 0; tn < 4; tn++) {
      const int n = nblock + wn + tn * 16 + quad * 4;
      if (n < 257) {
#pragma unroll
        for (int tm = 0; tm < 4; tm++) {
          const int token = mblock + wm + tm * 16 + l15;
          const f32x4 v = acc[tn][tm];
#pragma unroll
          for (int r = 0; r < 4; r++)
            if (n + r < 257) OutF[(size_t)token * 257 + n + r] = v[r];
        }
      }
    }
  }
}

// ---------------------------------------------------------------------------
extern "C" void kernel_launch(void* const* d_in, const int* in_sizes, int n_in,
                              void* d_out, int out_size, void* d_ws,
                              size_t ws_size, hipStream_t stream) {
  const int*   x    = (const int*)d_in[0];
  const float* emb  = (const float*)d_in[1];
  const float* we0  = (const float*)d_in[2];
  const float* we1  = (const float*)d_in[3];
  const float* we2  = (const float*)d_in[4];
  const float* we3  = (const float*)d_in[5];
  const float* we4  = (const float*)d_in[6];
  const float* we5  = (const float*)d_in[7];
  const float* we6  = (const float*)d_in[8];
  const float* we7  = (const float*)d_in[9];
  const float* wlay = (const float*)d_in[10];
  const float* wh   = (const float*)d_in[11];
  float* out = (float*)d_out;

  // workspace layout (~142 MiB)
  char* p = (char*)d_ws;
  auto alloc = [&](size_t bytes) {
    void* r = (void*)p;
    p += (bytes + 255) & ~(size_t)255;
    return r;
  };
  unsigned short* act0 = (unsigned short*)alloc(32768ull * 1024 * 2);
  unsigned short* act1 = (unsigned short*)alloc(32768ull * 1024 * 2);
  unsigned short* E4 = (unsigned short*)alloc(128 * 64 * 2);
  unsigned short* E5 = (unsigned short*)alloc(128 * 128 * 2);
  unsigned short* E6 = (unsigned short*)alloc(256 * 256 * 2);
  unsigned short* E7 = (unsigned short*)alloc(512 * 512 * 2);
  unsigned short* EL = (unsigned short*)alloc(6ull * 1024 * 1024 * 2);
  unsigned short* WH = (unsigned short*)alloc(384 * 1024 * 2);

  // zero the stability-loss slot (d_out is poisoned before every launch)
  hipMemsetAsync(out + 8421376, 0, 4, stream);

  // weight expansion (Hamilton blocks -> real fp16 matrices)
  expand_ham<<<dim3(8192 / 256), 256, 0, stream>>>(we4, E4, 16, 6, 128 * 64);
  expand_ham<<<dim3(16384 / 256), 256, 0, stream>>>(we5, E5, 32, 7, 128 * 128);
  expand_ham<<<dim3(65536 / 256), 256, 0, stream>>>(we6, E6, 64, 8, 256 * 256);
  expand_ham<<<dim3(262144 / 256), 256, 0, stream>>>(we7, E7, 128, 9,
                                                     512 * 512);
  for (int d = 0; d < 6; d++)
    expand_ham<<<dim3(1048576 / 256), 256, 0, stream>>>(
        wlay + (size_t)d * 262144, EL + (size_t)d * 1048576, 256, 10, 1048576);
  conv_head<<<dim3(384 * 1024 / 256), 256, 0, stream>>>(wh, WH);

  // embed + expansion steps 0..3 -> act0 [32768][64] fp16
  embed_expand<<<dim3(128), 256, 0, stream>>>(x, emb, we0, we1, we2, we3, act0);

  // expansion steps 4..7 as fused GEMMs (grid x = n-tiles, y = token-tiles)
  gemm_epi<0><<<dim3(1, 256), 256, 0, stream>>>(E4, act0, act1, nullptr, 64,
                                                64, 128);
  gemm_epi<0><<<dim3(1, 256), 256, 0, stream>>>(E5, act1, act0, nullptr, 128,
                                                128, 256);
  gemm_epi<0><<<dim3(2, 256), 256, 0, stream>>>(E6, act0, act1, nullptr, 256,
                                                256, 512);
  gemm_epi<0><<<dim3(4, 256), 256, 0, stream>>>(E7, act1, act0, nullptr, 512,
                                                512, 1024);

  // 6 quaternion-linear + normalize layers (last also accumulates loss)
  unsigned short* a = act0;
  unsigned short* b = act1;
  for (int d = 0; d < 5; d++) {
    gemm_epi<1><<<dim3(8, 256), 256, 0, stream>>>(EL + (size_t)d * 1048576, a,
                                                  b, nullptr, 1024, 1024, 1024);
    unsigned short* t = a; a = b; b = t;
  }
  gemm_epi<2><<<dim3(8, 256), 256, 0, stream>>>(EL + 5ull * 1048576, a, b,
                                                out + 8421376, 1024, 1024,
                                                1024);
  { unsigned short* t = a; a = b; b = t; }

  // head: logits = h @ w_head^T  (N padded 257 -> 384, masked stores)
  gemm_epi<3><<<dim3(3, 256), 256, 0, stream>>>(WH, a, nullptr, out, 1024, 257,
                                                0);
}